// Round 4
// baseline (115.010 us; speedup 1.0000x reference)
//
#include <hip/hip_runtime.h>

// MultiAgentLinearLayer via bf16 MFMA, round 4: co-resident blocks for overlap.
// out[b,o] = sum_k W[agent[b],o,k]*x[b,k] + bias[agent[b],o]
// B=2048, I=O=512, 64 agents, fp32 in/out. Threshold 5.97e-2 permits bf16.
//
// R2/R3 plateaued at ~28us = ~3 TB/s: 256 blocks at 1 block/CU meant each
// block's serial head (compaction + X-gather into LDS) was dead time, and
// phases serialized at barriers with nothing co-resident to overlap them.
// This round:
//  - BN=64, 256 threads (4 waves, one 16-col subtile each), full K per wave
//    (no k-split -> no LDS reduction, no extra barrier).
//  - LDS ~73 KB -> 2 blocks/CU; grid 8 x 64 = 512 blocks -> staging of one
//    block overlaps the K-loop of its CU-mate; dispatch balance improves.
//  - 4-deep register prefetch on W (8 float4/lane in flight; ~64 KB/CU >>
//    ~7.4 KB BW-latency product at 8 waves/CU).
//  - Stage only mcount rows of X (garbage rows only feed acc elems never
//    stored -- each C elem maps to exactly one row).
//  - W read from HBM exactly once (each block owns a distinct 64x512 slab).

constexpr int BATCH  = 2048;
constexpr int NAGENT = 64;
constexpr int IN_F   = 512;
constexpr int OUT_F  = 512;

constexpr int BN  = 64;         // block n-tile
constexpr int MCH = 64;         // m rows per chunk (count<=64 w.h.p.; loop covers more)
constexpr int XS  = IN_F + 8;   // X LDS stride in bf16 elems (520) -> b128 conflict-free

typedef __attribute__((ext_vector_type(8))) short short8;     // bf16 A/B frag (4 VGPRs)
typedef __attribute__((ext_vector_type(4))) float f32x4;      // fp32 C/D frag
typedef __attribute__((ext_vector_type(4))) unsigned int u32x4;

__device__ inline unsigned rnd_bf(float f) {
  // fp32 -> bf16 RTN, result in high 16 bits
  unsigned u = __float_as_uint(f);
  return u + 0x7FFFu + ((u >> 16) & 1u);
}
__device__ inline unsigned pk_bf(float lo, float hi) {
  return (rnd_bf(lo) >> 16) | (rnd_bf(hi) & 0xFFFF0000u);
}

__global__ __launch_bounds__(256, 2) void agent_linear_v4(
    const int*   __restrict__ which,
    const float* __restrict__ x,
    const float* __restrict__ weight,
    const float* __restrict__ bias,
    float*       __restrict__ out) {
  const int tid   = threadIdx.x;
  const int lane  = tid & 63;
  const int wid   = tid >> 6;        // 0..3 (n-subtile)
  const int agent = blockIdx.y;
  const int obase = blockIdx.x * BN;

  __shared__ int wsum_s[4];
  __shared__ int rowlist_s[BATCH];                       // 8 KB
  __shared__ __align__(16) unsigned short Xs[MCH * XS];  // 65 KB bf16

  // ---- stable compaction: rows with which[i]==agent, ascending ----
  int vals[8];
  {
    const int4* w4 = (const int4*)which;
    int4 v0 = w4[tid * 2];
    int4 v1 = w4[tid * 2 + 1];
    vals[0] = v0.x; vals[1] = v0.y; vals[2] = v0.z; vals[3] = v0.w;
    vals[4] = v1.x; vals[5] = v1.y; vals[6] = v1.z; vals[7] = v1.w;
  }
  int lc = 0;
#pragma unroll
  for (int u = 0; u < 8; ++u) lc += (vals[u] == agent) ? 1 : 0;
  int s = lc;
#pragma unroll
  for (int off = 1; off < 64; off <<= 1) {
    int t = __shfl_up(s, off);
    if (lane >= off) s += t;
  }
  if (lane == 63) wsum_s[wid] = s;
  __syncthreads();
  int base = 0, count = 0;
#pragma unroll
  for (int w = 0; w < 4; ++w) {
    int ws = wsum_s[w];
    if (w < wid) base += ws;
    count += ws;
  }
  {
    int pos = base + s - lc;
#pragma unroll
    for (int u = 0; u < 8; ++u)
      if (vals[u] == agent) rowlist_s[pos++] = tid * 8 + u;
  }
  __syncthreads();   // rowlist_s ready

  const int nl = lane & 15;      // n within frag / m within A-frag
  const int kq = lane >> 4;      // k-quad 0..3

  const float* wp = weight + ((size_t)(agent * OUT_F + obase + wid * 16 + nl)) * IN_F + kq * 8;
  const float  bv = bias[agent * OUT_F + obase + wid * 16 + nl];

  for (int m0 = 0; m0 < count; m0 += MCH) {
    const int mcount = min(MCH, count - m0);
    __syncthreads();   // prior iter's Xs reads done before restaging

    // ---- stage X chunk: mcount rows x 512 k as bf16 (wave-uniform row guard) ----
#pragma unroll 4
    for (int t = 0; t < 32; ++t) {
      int idx = t * 256 + tid;
      int r   = idx >> 7;          // 0..63, uniform per half-wave
      int c4  = idx & 127;         // float4 column
      if (r < mcount) {
        float4 xv = *(const float4*)(x + (size_t)rowlist_s[m0 + r] * IN_F + c4 * 4);
        uint2 w2;
        w2.x = pk_bf(xv.x, xv.y);
        w2.y = pk_bf(xv.z, xv.w);
        *(uint2*)&Xs[r * XS + c4 * 4] = w2;
      }
    }
    __syncthreads();

    // ---- barrier-free K-loop, full K=512, 4-deep W prefetch ----
    f32x4 acc[4] = {{0.f,0.f,0.f,0.f},{0.f,0.f,0.f,0.f},
                    {0.f,0.f,0.f,0.f},{0.f,0.f,0.f,0.f}};
    float4 pa[4], pb[4];
#pragma unroll
    for (int p = 0; p < 4; ++p) {
      pa[p] = *(const float4*)(wp + p * 32);
      pb[p] = *(const float4*)(wp + p * 32 + 4);
    }
#pragma unroll
    for (int k = 0; k < 16; ++k) {
      float4 c0 = pa[k & 3], c1 = pb[k & 3];
      if (k + 4 < 16) {
        pa[k & 3] = *(const float4*)(wp + (k + 4) * 32);
        pb[k & 3] = *(const float4*)(wp + (k + 4) * 32 + 4);
      }
      u32x4 q;
      q[0] = pk_bf(c0.x, c0.y); q[1] = pk_bf(c0.z, c0.w);
      q[2] = pk_bf(c1.x, c1.y); q[3] = pk_bf(c1.z, c1.w);
      short8 bf = __builtin_bit_cast(short8, q);
#pragma unroll
      for (int i = 0; i < 4; ++i) {
        short8 af = *(const short8*)&Xs[(i * 16 + nl) * XS + k * 32 + kq * 8];
        acc[i] = __builtin_amdgcn_mfma_f32_16x16x32_bf16(af, bf, acc[i], 0, 0, 0);
      }
    }

    // ---- epilogue: D row=(lane>>4)*4+reg, col=lane&15 ----
#pragma unroll
    for (int i = 0; i < 4; ++i) {
#pragma unroll
      for (int r = 0; r < 4; ++r) {
        int m = i * 16 + kq * 4 + r;
        if (m < mcount) {
          out[(size_t)rowlist_s[m0 + m] * OUT_F + obase + wid * 16 + nl] =
              acc[i][r] + bv;
        }
      }
    }
  }
}

extern "C" void kernel_launch(void* const* d_in, const int* in_sizes, int n_in,
                              void* d_out, int out_size, void* d_ws, size_t ws_size,
                              hipStream_t stream) {
  const int*   which = (const int*)d_in[0];
  const float* x     = (const float*)d_in[1];
  const float* w     = (const float*)d_in[2];
  const float* b     = (const float*)d_in[3];
  float*       out   = (float*)d_out;

  dim3 grid(OUT_F / BN, NAGENT);   // 8 x 64 = 512 blocks, 2 per CU
  agent_linear_v4<<<grid, dim3(256), 0, stream>>>(which, x, w, b, out);
}